// Round 10
// baseline (2448.052 us; speedup 1.0000x reference)
//
#include <hip/hip_runtime.h>
#include <stdint.h>

#define N_NODES   50000
#define N_GENES   512
#define N_EDGES   800000
#define N_ITERS   5

#define C_CHUNKS  125
#define CHUNK_E   6400          // 125 * 6400 = 800000; 6400/64 = 100 subchunks

#define PSTRIDE   224           // packed values per row (max nnz ~212)
#define HDR_W     20            // u32/row: [0..3]=pfx u8x16, [4..19]=mask bits

// ws layout (bytes)
#define PV_BYTES    ((size_t)N_NODES * PSTRIDE * 4)   // 44.8 MB
#define HDR_BYTES   ((size_t)N_NODES * HDR_W * 4)     // 4 MB
#define IMP_BYTES   3200000ull
#define CNT_BYTES   200000ull
#define PTR_BYTES   200004ull
#define CCOL_BYTES  3200000ull
#define CW_BYTES    3200000ull
#define WS_NEEDED (2*PV_BYTES + 2*HDR_BYTES + IMP_BYTES + CNT_BYTES + PTR_BYTES + CCOL_BYTES + CW_BYTES)
// chunk-hist (125*50000*4 = 25 MB) aliases pv0; dead before pack_initial writes pv0.

// ---------- JAX threefry2x32 (20 rounds), exact replica ----------
__host__ __device__ __forceinline__ uint32_t rotl32(uint32_t x, int r) {
  return (x << r) | (x >> (32 - r));
}

__host__ __device__ __forceinline__ void threefry2x32(uint32_t k0, uint32_t k1,
                                                      uint32_t x0, uint32_t x1,
                                                      uint32_t& o0, uint32_t& o1) {
  uint32_t k2 = k0 ^ k1 ^ 0x1BD11BDAu;
  x0 += k0; x1 += k1;
  x0 += x1; x1 = rotl32(x1, 13) ^ x0;
  x0 += x1; x1 = rotl32(x1, 15) ^ x0;
  x0 += x1; x1 = rotl32(x1, 26) ^ x0;
  x0 += x1; x1 = rotl32(x1, 6)  ^ x0;
  x0 += k1; x1 += k2 + 1u;
  x0 += x1; x1 = rotl32(x1, 17) ^ x0;
  x0 += x1; x1 = rotl32(x1, 29) ^ x0;
  x0 += x1; x1 = rotl32(x1, 16) ^ x0;
  x0 += x1; x1 = rotl32(x1, 24) ^ x0;
  x0 += k2; x1 += k0 + 2u;
  x0 += x1; x1 = rotl32(x1, 13) ^ x0;
  x0 += x1; x1 = rotl32(x1, 15) ^ x0;
  x0 += x1; x1 = rotl32(x1, 26) ^ x0;
  x0 += x1; x1 = rotl32(x1, 6)  ^ x0;
  x0 += k0; x1 += k1 + 3u;
  x0 += x1; x1 = rotl32(x1, 17) ^ x0;
  x0 += x1; x1 = rotl32(x1, 29) ^ x0;
  x0 += x1; x1 = rotl32(x1, 16) ^ x0;
  x0 += x1; x1 = rotl32(x1, 24) ^ x0;
  x0 += k1; x1 += k2 + 4u;
  x0 += x1; x1 = rotl32(x1, 13) ^ x0;
  x0 += x1; x1 = rotl32(x1, 15) ^ x0;
  x0 += x1; x1 = rotl32(x1, 26) ^ x0;
  x0 += x1; x1 = rotl32(x1, 6)  ^ x0;
  x0 += k2; x1 += k0 + 5u;
  o0 = x0; o1 = x1;
}

// threefry_partitionable=True 32-bit bits: counter (0,j), xor-fold o0^o1.
__device__ __forceinline__ uint32_t jax_bits_part32(uint32_t k0, uint32_t k1, uint32_t j) {
  uint32_t o0, o1;
  threefry2x32(k0, k1, 0u, j, o0, o1);
  return o0 ^ o1;
}

// ---------- order-preserving CSR build ----------
__global__ void chunk_hist(const int* __restrict__ rows, int* __restrict__ hist) {
  int c = blockIdx.x;
  int base = c * CHUNK_E;
  int* h = hist + (size_t)c * N_NODES;
  for (int i = threadIdx.x; i < CHUNK_E; i += blockDim.x)
    atomicAdd(&h[rows[base + i]], 1);
}

__global__ void row_scan(int* __restrict__ hist, int* __restrict__ cnt) {
  int r = blockIdx.x * blockDim.x + threadIdx.x;
  if (r >= N_NODES) return;
  int run = 0;
  for (int c = 0; c < C_CHUNKS; ++c) {
    size_t idx = (size_t)c * N_NODES + r;
    int t = hist[idx];
    hist[idx] = run;
    run += t;
  }
  cnt[r] = run;
}

__global__ void scan_counts(int* __restrict__ cnt, int* __restrict__ ptr) {
  const int T = 256;
  const int CH = (N_NODES + T - 1) / T;  // 196
  __shared__ int sums[T];
  int t = threadIdx.x;
  int lo = t * CH;
  int hi = min(lo + CH, N_NODES);
  int s = 0;
  for (int i = lo; i < hi; ++i) s += cnt[i];
  sums[t] = s;
  __syncthreads();
  for (int off = 1; off < T; off <<= 1) {
    int u = (t >= off) ? sums[t - off] : 0;
    __syncthreads();
    sums[t] += u;
    __syncthreads();
  }
  int run = sums[t] - s;
  for (int i = lo; i < hi; ++i) { int c = cnt[i]; ptr[i] = run; run += c; }
  if (t == T - 1) ptr[N_NODES] = run;
}

// parallel order-preserving scatter: one wave per chunk (R6 notes).
__global__ __launch_bounds__(64) void scatter_par(
    const int* __restrict__ rows, const int* __restrict__ cols,
    const float* __restrict__ w, const int* __restrict__ ptr,
    int* __restrict__ hist, int* __restrict__ ccol, float* __restrict__ cw) {
  int c = blockIdx.x;
  int lane = threadIdx.x;
  int* h = hist + (size_t)c * N_NODES;
  int base = c * CHUNK_E;
  for (int sub = 0; sub < CHUNK_E / 64; ++sub) {
    int e = base + sub * 64 + lane;
    int r = rows[e];
    int rank = 0, count = 0, lastlane = 0;
    #pragma unroll 8
    for (int i = 0; i < 64; ++i) {
      int ri = __shfl(r, i, 64);
      if (ri == r) {
        count++;
        if (i < lane) rank++;
        lastlane = i;
      }
    }
    int old = 0;
    if (lane == lastlane) old = atomicAdd(&h[r], count);
    old = __shfl(old, lastlane, 64);   // data dep -> vmcnt drain before next sub
    int pos = ptr[r] + old + rank;
    ccol[pos] = cols[e];
    cw[pos]   = w[e];
  }
}

// transposed LDS index for bucket b
__device__ __forceinline__ int tr(uint32_t b) {
  return (int)(((b & 3u) << 6) | (b >> 2));
}

// pack a row (lane owns genes 8*lane..8*lane+7) into hdr/pval
__device__ __forceinline__ void pack_row(int lane, size_t r, const float rv[8],
                                         uint32_t* __restrict__ hdr,
                                         float* __restrict__ pval) {
  uint32_t nm8 = 0;
  #pragma unroll
  for (int j = 0; j < 8; ++j)
    if (rv[j] != 0.f) nm8 |= (1u << j);
  int pc = __popc(nm8);
  int incl = pc;
  #pragma unroll
  for (int off = 1; off < 64; off <<= 1) {
    int v = __shfl_up(incl, off, 64);
    if (lane >= off) incl += v;
  }
  int basew = incl - pc;   // nnz before gene 8*lane
  float* pr = pval + r * PSTRIDE;
  #pragma unroll
  for (int j = 0; j < 8; ++j) {
    if (nm8 & (1u << j)) {
      int idx = basew + __popc(nm8 & ((1u << j) - 1u));
      if (idx < PSTRIDE) pr[idx] = rv[j];
    }
  }
  // mask word for 4-lane group
  uint32_t wordv = nm8 << (8 * (lane & 3));
  wordv |= (uint32_t)__shfl_xor((int)wordv, 1, 64);
  wordv |= (uint32_t)__shfl_xor((int)wordv, 2, 64);
  // pfx word (4 bytes = bases of lanes lq, lq+4, lq+8, lq+12)
  int lq = lane & 48;
  uint32_t p0 = (uint32_t)__shfl(basew, lq, 64);
  uint32_t p1 = (uint32_t)__shfl(basew, (lq + 4) & 63, 64);
  uint32_t p2 = (uint32_t)__shfl(basew, (lq + 8) & 63, 64);
  uint32_t p3 = (uint32_t)__shfl(basew, (lq + 12) & 63, 64);
  uint32_t pfxword = p0 | (p1 << 8) | (p2 << 16) | (p3 << 24);
  uint32_t* hr = hdr + r * HDR_W;
  if ((lane & 3) == 0)  hr[4 + (lane >> 2)] = wordv;
  if ((lane & 15) == 0) hr[lane >> 4] = pfxword;
}

// unpack lane's 8 genes of row ci: returns m8; fills v[8] (0 where bit clear)
__device__ __forceinline__ uint32_t unpack_row(int lane, size_t ci,
                                               const uint32_t* __restrict__ hdr,
                                               const float* __restrict__ pval,
                                               float v[8]) {
  const uint32_t* hd = hdr + ci * HDR_W;
  uint32_t mw = hd[4 + (lane >> 2)];
  uint32_t pw = hd[lane >> 4];
  uint32_t pfx = (pw >> (8 * ((lane >> 2) & 3))) & 0xFFu;
  uint32_t m8 = (mw >> (8 * (lane & 3))) & 0xFFu;
  uint32_t below = (lane & 3) ? ((1u << (8 * (lane & 3))) - 1u) : 0u;
  int rbase = (int)pfx + __popc(mw & below);
  const float* pr = pval + ci * PSTRIDE;
  #pragma unroll
  for (int j = 0; j < 8; ++j) {
    v[j] = 0.f;
    if (m8 & (1u << j))
      v[j] = pr[rbase + __popc(m8 & ((1u << j) - 1u))];
  }
  return m8;
}

// initial pack: dense x_in -> packed (mask/pfx/values)
__global__ __launch_bounds__(256) void pack_initial(
    const float* __restrict__ x_in, uint32_t* __restrict__ hdr,
    float* __restrict__ pval) {
  int wv = threadIdx.x >> 6;
  int lane = threadIdx.x & 63;
  size_t r = (size_t)blockIdx.x * 4 + wv;
  if (r >= N_NODES) return;
  const float4* xr = (const float4*)(x_in + r * N_GENES);
  float4 a = xr[2 * lane], b = xr[2 * lane + 1];
  float rv[8] = {a.x, a.y, a.z, a.w, b.x, b.y, b.z, b.w};
  pack_row(lane, r, rv, hdr, pval);
}

// ---------- fused propagate + select on packed x: one wave per row ----------
// Zero-skip is exact: acc + w*(+0.0) == acc bit-exactly; -0/+0 flips cannot
// affect any comparison or absmax. Chain order per (row,gene) over nonzero
// edges preserved (ascending edge order; mul/add rounded separately).
__global__ __launch_bounds__(256) void prop_select(
    const uint32_t* __restrict__ hdr_prev, const float* __restrict__ pv_prev,
    const int* __restrict__ ptr, const int* __restrict__ ccol,
    const float* __restrict__ cw, unsigned char* __restrict__ imp,
    const int* __restrict__ cap_arr, uint32_t k0, uint32_t k1,
    uint32_t* __restrict__ hdr_next, float* __restrict__ pv_next,
    float* __restrict__ xdense, int write_dense) {
  #pragma clang fp contract(off)
  __shared__ int hist_s[4][256];
  int wv = threadIdx.x >> 6;
  int lane = threadIdx.x & 63;
  size_t r = (size_t)blockIdx.x * 4 + wv;
  if (r >= N_NODES) return;
  int beg = ptr[r], end = ptr[r + 1];
  int* h = hist_s[wv];
  unsigned char ibyte = imp[r * 64 + lane];
  int cap = cap_arr[r];

  // own-row unpack (merge inputs) before the gather to overlap latency
  float pvrow[8];
  uint32_t m8r = unpack_row(lane, r, hdr_prev, pv_prev, pvrow);

  // ---- gather-accumulate over packed neighbor rows ----
  float acc[8] = {0.f, 0.f, 0.f, 0.f, 0.f, 0.f, 0.f, 0.f};
  for (int base_e = beg; base_e < end; base_e += 64) {
    int n = min(64, end - base_e);
    int c = 0; float wt = 0.f;
    if (lane < n) { c = ccol[base_e + lane]; wt = cw[base_e + lane]; }
    for (int i = 0; i < n; ++i) {
      size_t ci = (size_t)__shfl(c, i, 64);
      float wi = __shfl(wt, i, 64);
      const uint32_t* hd = hdr_prev + ci * HDR_W;
      uint32_t mw = hd[4 + (lane >> 2)];
      uint32_t pw = hd[lane >> 4];
      uint32_t pfx = (pw >> (8 * ((lane >> 2) & 3))) & 0xFFu;
      uint32_t m8 = (mw >> (8 * (lane & 3))) & 0xFFu;
      uint32_t below = (lane & 3) ? ((1u << (8 * (lane & 3))) - 1u) : 0u;
      int rbase = (int)pfx + __popc(mw & below);
      const float* pr = pv_prev + ci * PSTRIDE;
      #pragma unroll
      for (int j = 0; j < 8; ++j) {
        if (m8 & (1u << j)) {
          float v = pr[rbase + __popc(m8 & ((1u << j) - 1u))];
          acc[j] = acc[j] + wi * v;
        }
      }
    }
  }

  // ---- merge: existing <=> maskbit && !impbit (== orig != 0) ----
  float val[8];
  bool ex[8];
  bool valid[8];
  int cnt_local = 0;
  #pragma unroll
  for (int j = 0; j < 8; ++j) {
    bool mb = (m8r >> j) & 1;
    bool ib = (ibyte >> j) & 1;
    ex[j] = mb && !ib;
    val[j] = ex[j] ? pvrow[j] : acc[j];
    bool im = ib || ((val[j] != 0.f) && !ex[j]);
    valid[j] = im;
    cnt_local += im ? 1 : 0;
  }
  int nimp = cnt_local;
  #pragma unroll
  for (int off = 32; off > 0; off >>= 1) nimp += __shfl_xor(nimp, off, 64);

  bool keep_all = (nimp <= cap);
  bool keep_none = (!keep_all) && (cap <= 0);
  uint32_t key[8];
  uint32_t T = 0;
  bool use_T = false;

  if (!keep_all && !keep_none) {   // wave-uniform branch
    #pragma unroll
    for (int j = 0; j < 8; ++j) {
      uint32_t g = (uint32_t)(8 * lane + j);
      uint32_t b = jax_bits_part32(k0, k1, (uint32_t)(r * N_GENES) + g);
      key[j] = ((b >> 9) << 9) | g;    // (score23, gene), distinct
    }
    h[lane] = 0; h[lane + 64] = 0; h[lane + 128] = 0; h[lane + 192] = 0;
    #pragma unroll
    for (int j = 0; j < 8; ++j)
      if (valid[j]) atomicAdd(&h[tr(key[j] >> 24)], 1);
    __threadfence_block();
    int c0 = h[lane], c1 = h[64 + lane], c2 = h[128 + lane], c3 = h[192 + lane];
    int lsum = c0 + c1 + c2 + c3;
    int incl = lsum;
    #pragma unroll
    for (int off = 1; off < 64; off <<= 1) {
      int v = __shfl_up(incl, off, 64);
      if (lane >= off) incl += v;
    }
    int excl = incl - lsum;
    int foundB = -1, foundRem = 0, cum = excl;
    if (cap > cum && cap <= cum + c0) { foundB = 4 * lane;     foundRem = cap - cum; } cum += c0;
    if (foundB < 0 && cap > cum && cap <= cum + c1) { foundB = 4 * lane + 1; foundRem = cap - cum; } cum += c1;
    if (foundB < 0 && cap > cum && cap <= cum + c2) { foundB = 4 * lane + 2; foundRem = cap - cum; } cum += c2;
    if (foundB < 0 && cap > cum && cap <= cum + c3) { foundB = 4 * lane + 3; foundRem = cap - cum; }
    unsigned long long mb = __ballot(foundB >= 0);
    int src = __ffsll(mb) - 1;
    int B   = __shfl(foundB, src, 64);
    int rem = __shfl(foundRem, src, 64);
    unsigned cm = 0;
    #pragma unroll
    for (int j = 0; j < 8; ++j)
      if (valid[j] && (int)(key[j] >> 24) == B) cm |= (1u << j);
    for (;;) {
      uint32_t m = 0xFFFFFFFFu;
      #pragma unroll
      for (int j = 0; j < 8; ++j)
        if (cm & (1u << j)) m = min(m, key[j]);
      #pragma unroll
      for (int off = 32; off > 0; off >>= 1)
        m = min(m, (uint32_t)__shfl_xor((int)m, off, 64));
      if (rem == 1) { T = m; break; }
      #pragma unroll
      for (int j = 0; j < 8; ++j)
        if ((cm & (1u << j)) && key[j] == m) cm &= ~(1u << j);
      rem--;
    }
    use_T = true;
  }

  // ---- apply, pack, write ----
  float rv[8]; unsigned char ob8 = 0;
  #pragma unroll
  for (int j = 0; j < 8; ++j) {
    bool keep = valid[j] && (keep_all || (use_T && key[j] <= T));
    ob8 |= (unsigned char)(keep ? (1u << j) : 0u);
    rv[j] = (valid[j] && !keep) ? 0.f : val[j];
  }
  pack_row(lane, r, rv, hdr_next, pv_next);
  imp[r * 64 + lane] = ob8;
  if (write_dense) {
    float* xd = xdense + r * N_GENES + 8 * lane;
    #pragma unroll
    for (int j = 0; j < 8; ++j) xd[j] = rv[j];
  }
}

// diagnostic: only fires if workspace is smaller than we need
__global__ void ws_probe(float* out, unsigned long long ws_bytes, unsigned long long needed) {
  if (ws_bytes < needed) out[0] = (float)ws_bytes;
}

extern "C" void kernel_launch(void* const* d_in, const int* in_sizes, int n_in,
                              void* d_out, int out_size, void* d_ws, size_t ws_size,
                              hipStream_t stream) {
  const float* x_in = (const float*)d_in[0];
  const float* ew   = (const float*)d_in[1];
  const int*   ei   = (const int*)d_in[2];
  const int*   cap  = (const int*)d_in[3];
  const int* rows = ei;
  const int* cols = ei + N_EDGES;
  float* out = (float*)d_out;

  char* ws = (char*)d_ws;
  float*    pv0  = (float*)ws;          ws += PV_BYTES;
  float*    pv1  = (float*)ws;          ws += PV_BYTES;
  uint32_t* hdr0 = (uint32_t*)ws;       ws += HDR_BYTES;
  uint32_t* hdr1 = (uint32_t*)ws;       ws += HDR_BYTES;
  unsigned char* imp = (unsigned char*)ws; ws += IMP_BYTES;
  int* cnt  = (int*)ws;                 ws += CNT_BYTES;
  int* ptr  = (int*)ws;                 ws += PTR_BYTES;
  int* ccol = (int*)ws;                 ws += CCOL_BYTES;
  float* cw = (float*)ws;               ws += CW_BYTES;
  int* hist = (int*)d_ws;  // aliases pv0 (25 MB); dead before pack_initial

  hipMemsetAsync(hist, 0, (size_t)C_CHUNKS * N_NODES * sizeof(int), stream);
  hipMemsetAsync(imp, 0, IMP_BYTES, stream);

  chunk_hist<<<C_CHUNKS, 256, 0, stream>>>(rows, hist);
  row_scan<<<(N_NODES + 255) / 256, 256, 0, stream>>>(hist, cnt);
  scan_counts<<<1, 256, 0, stream>>>(cnt, ptr);
  scatter_par<<<C_CHUNKS, 64, 0, stream>>>(rows, cols, ew, ptr, hist, ccol, cw);
  pack_initial<<<(N_NODES + 3) / 4, 256, 0, stream>>>(x_in, hdr0, pv0);

  // per-iteration keys: fold_in(key(42), it) = threefry2x32((0,42),(0,it))
  uint32_t key_it[N_ITERS][2];
  for (int it = 0; it < N_ITERS; ++it) {
    uint32_t o0, o1;
    threefry2x32(0u, 42u, 0u, (uint32_t)it, o0, o1);
    key_it[it][0] = o0; key_it[it][1] = o1;
  }

  for (int it = 0; it < N_ITERS; ++it) {
    const uint32_t* hp = (it & 1) ? hdr1 : hdr0;
    const float*    pp = (it & 1) ? pv1  : pv0;
    uint32_t* hn = (it & 1) ? hdr0 : hdr1;
    float*    pn = (it & 1) ? pv0  : pv1;
    int wd = (it == N_ITERS - 1) ? 1 : 0;
    prop_select<<<(N_NODES + 3) / 4, 256, 0, stream>>>(
        hp, pp, ptr, ccol, cw, imp, cap,
        key_it[it][0], key_it[it][1], hn, pn, out, wd);
  }

  ws_probe<<<1, 1, 0, stream>>>(out, (unsigned long long)ws_size,
                                (unsigned long long)WS_NEEDED);
}